// Round 1
// baseline (2595.443 us; speedup 1.0000x reference)
//
#include <hip/hip_runtime.h>
#include <hip/hip_bf16.h>

#define IN_FEATS 22
#define HID 16
#define FCH 8
#define NG 256

__device__ __forceinline__ void atomAddF(float* p, float v) {
#if defined(__HIP_PLATFORM_AMD__)
    unsafeAtomicAdd(p, v);   // HW global_atomic_add_f32 on gfx90a+
#else
    atomicAdd(p, v);
#endif
}

// y1[node][f] = sum_k h[node][k] * W1[k][f]   (W1 stored [in,out] row-major)
__global__ __launch_bounds__(256) void proj1_kernel(
    const float* __restrict__ h, const float* __restrict__ W1,
    float* __restrict__ y1, int n) {
    int t = blockIdx.x * blockDim.x + threadIdx.x;
    int total = n * HID;
    int stride = gridDim.x * blockDim.x;
    for (int s = t; s < total; s += stride) {
        int node = s >> 4, f = s & 15;
        const float* hr = h + (long long)node * IN_FEATS;
        float acc = 0.f;
#pragma unroll
        for (int k = 0; k < IN_FEATS; ++k) acc += hr[k] * W1[k * HID + f];
        y1[s] = acc;
    }
}

// lane slot s -> edge e = s/16, feat f = s%16. Gather y[src[e]][f], atomic-add
// into agg[dst[e]][f]. Optionally count in-degree (once, layer 1).
template <bool COUNT_DEG>
__global__ __launch_bounds__(256) void scatter_kernel(
    const int* __restrict__ src, const int* __restrict__ dst,
    const float* __restrict__ y, float* __restrict__ agg,
    float* __restrict__ deg, int n_edges) {
    int t = blockIdx.x * blockDim.x + threadIdx.x;
    int total = n_edges * HID;           // 256M < 2^31
    int stride = gridDim.x * blockDim.x;
    for (int s = t; s < total; s += stride) {
        int e = s >> 4, f = s & 15;
        int sn = src[e], dn = dst[e];
        float v = y[(long long)sn * HID + f];
        atomAddF(&agg[(long long)dn * HID + f], v);
        if (COUNT_DEG && f == 0) atomAddF(&deg[dn], 1.0f);
    }
}

// x1 = relu(where(deg>0, agg/deg, y1) + b1); y2 = x1 @ W2  (written over y1)
__global__ __launch_bounds__(256) void finish1_kernel(
    const float* __restrict__ agg, const float* __restrict__ deg,
    float* __restrict__ y, const float* __restrict__ b1,
    const float* __restrict__ W2, int n) {
    int i = blockIdx.x * blockDim.x + threadIdx.x;
    int stride = gridDim.x * blockDim.x;
    for (; i < n; i += stride) {
        float d = deg[i];
        float inv = d > 0.f ? 1.f / d : 0.f;
        bool mail = d > 0.f;
        const float4* ag = (const float4*)(agg + (long long)i * HID);
        const float4* yy = (const float4*)(y + (long long)i * HID);
        float x1[HID];
#pragma unroll
        for (int q = 0; q < 4; ++q) {
            float4 a = ag[q];
            float4 b = yy[q];
            float v0 = mail ? a.x * inv : b.x;
            float v1 = mail ? a.y * inv : b.y;
            float v2 = mail ? a.z * inv : b.z;
            float v3 = mail ? a.w * inv : b.w;
            x1[q * 4 + 0] = fmaxf(v0 + b1[q * 4 + 0], 0.f);
            x1[q * 4 + 1] = fmaxf(v1 + b1[q * 4 + 1], 0.f);
            x1[q * 4 + 2] = fmaxf(v2 + b1[q * 4 + 2], 0.f);
            x1[q * 4 + 3] = fmaxf(v3 + b1[q * 4 + 3], 0.f);
        }
        float out[HID];
#pragma unroll
        for (int f = 0; f < HID; ++f) out[f] = 0.f;
#pragma unroll
        for (int k = 0; k < HID; ++k) {
            float xv = x1[k];
#pragma unroll
            for (int f = 0; f < HID; ++f) out[f] += xv * W2[k * HID + f];
        }
        float4* dst4 = (float4*)(y + (long long)i * HID);
#pragma unroll
        for (int q = 0; q < 4; ++q)
            dst4[q] = make_float4(out[q * 4 + 0], out[q * 4 + 1],
                                  out[q * 4 + 2], out[q * 4 + 3]);
    }
}

// x2 = relu(where(deg>0, agg/deg, y2) + b2)   (written over y2)
__global__ __launch_bounds__(256) void finish2_kernel(
    const float* __restrict__ agg, const float* __restrict__ deg,
    float* __restrict__ y, const float* __restrict__ b2, int n) {
    int i = blockIdx.x * blockDim.x + threadIdx.x;
    int stride = gridDim.x * blockDim.x;
    for (; i < n; i += stride) {
        float d = deg[i];
        float inv = d > 0.f ? 1.f / d : 0.f;
        bool mail = d > 0.f;
        const float4* ag = (const float4*)(agg + (long long)i * HID);
        float4* yy = (float4*)(y + (long long)i * HID);
#pragma unroll
        for (int q = 0; q < 4; ++q) {
            float4 a = ag[q];
            float4 b = yy[q];
            float v0 = mail ? a.x * inv : b.x;
            float v1 = mail ? a.y * inv : b.y;
            float v2 = mail ? a.z * inv : b.z;
            float v3 = mail ? a.w * inv : b.w;
            yy[q] = make_float4(fmaxf(v0 + b2[q * 4 + 0], 0.f),
                                fmaxf(v1 + b2[q * 4 + 1], 0.f),
                                fmaxf(v2 + b2[q * 4 + 2], 0.f),
                                fmaxf(v3 + b2[q * 4 + 3], 0.f));
        }
    }
}

// Block g: binary-search [lo,hi) of graph g in sorted graph_ids, mean-pool x2,
// then FC(16->8) -> FC(8->1) -> sigmoid.
__global__ __launch_bounds__(256) void pool_fc_kernel(
    const float* __restrict__ x2, const int* __restrict__ gid, int n,
    const float* __restrict__ Wf1, const float* __restrict__ bf1,
    const float* __restrict__ Wf2, const float* __restrict__ bf2,
    float* __restrict__ out) {
    int g = blockIdx.x;
    int lo, hi;
    {
        int a = 0, b = n;
        while (a < b) { int m = (a + b) >> 1; if (gid[m] < g) a = m + 1; else b = m; }
        lo = a;
        b = n;
        while (a < b) { int m = (a + b) >> 1; if (gid[m] < g + 1) a = m + 1; else b = m; }
        hi = a;
    }
    int cnt = hi - lo;
    float acc[HID];
#pragma unroll
    for (int k = 0; k < HID; ++k) acc[k] = 0.f;
    for (int i = lo + threadIdx.x; i < hi; i += blockDim.x) {
        const float4* p = (const float4*)(x2 + (long long)i * HID);
#pragma unroll
        for (int q = 0; q < 4; ++q) {
            float4 v = p[q];
            acc[q * 4 + 0] += v.x; acc[q * 4 + 1] += v.y;
            acc[q * 4 + 2] += v.z; acc[q * 4 + 3] += v.w;
        }
    }
    __shared__ float smem[256][HID];
#pragma unroll
    for (int k = 0; k < HID; ++k) smem[threadIdx.x][k] = acc[k];
    __syncthreads();
    for (int off = 128; off > 0; off >>= 1) {
        if (threadIdx.x < off)
            for (int k = 0; k < HID; ++k)
                smem[threadIdx.x][k] += smem[threadIdx.x + off][k];
        __syncthreads();
    }
    if (threadIdx.x == 0) {
        float inv = cnt > 0 ? 1.f / (float)cnt : 0.f;
        float hg[HID];
        for (int k = 0; k < HID; ++k) hg[k] = smem[0][k] * inv;
        float f1[FCH];
        for (int j = 0; j < FCH; ++j) {
            float a = bf1[j];
            for (int k = 0; k < HID; ++k) a += hg[k] * Wf1[k * FCH + j];
            f1[j] = a;
        }
        float o = bf2[0];
        for (int j = 0; j < FCH; ++j) o += f1[j] * Wf2[j];
        out[g] = 1.f / (1.f + expf(-o));
    }
}

extern "C" void kernel_launch(void* const* d_in, const int* in_sizes, int n_in,
                              void* d_out, int out_size, void* d_ws, size_t ws_size,
                              hipStream_t stream) {
    const float* h   = (const float*)d_in[0];
    const int*   src = (const int*)d_in[1];
    const int*   dst = (const int*)d_in[2];
    const int*   gid = (const int*)d_in[3];
    const float* W1  = (const float*)d_in[4];
    const float* b1  = (const float*)d_in[5];
    const float* W2  = (const float*)d_in[6];
    const float* b2  = (const float*)d_in[7];
    const float* Wf1 = (const float*)d_in[8];
    const float* bf1 = (const float*)d_in[9];
    const float* Wf2 = (const float*)d_in[10];
    const float* bf2 = (const float*)d_in[11];
    float* out = (float*)d_out;

    int n       = in_sizes[3];   // graph_ids length == N_NODES
    int n_edges = in_sizes[1];

    char* ws = (char*)d_ws;
    float* bufA = (float*)ws;                                  // n*16 f32
    float* bufB = (float*)(ws + (size_t)n * HID * 4);          // n*16 f32
    float* deg  = (float*)(ws + (size_t)n * HID * 8);          // n f32

    hipMemsetAsync(bufB, 0, (size_t)n * HID * 4, stream);
    hipMemsetAsync(deg, 0, (size_t)n * 4, stream);

    proj1_kernel<<<4096, 256, 0, stream>>>(h, W1, bufA, n);
    scatter_kernel<true><<<8192, 256, 0, stream>>>(src, dst, bufA, bufB, deg, n_edges);
    finish1_kernel<<<4096, 256, 0, stream>>>(bufB, deg, bufA, b1, W2, n);
    hipMemsetAsync(bufB, 0, (size_t)n * HID * 4, stream);
    scatter_kernel<false><<<8192, 256, 0, stream>>>(src, dst, bufA, bufB, deg, n_edges);
    finish2_kernel<<<4096, 256, 0, stream>>>(bufB, deg, bufA, b2, n);
    pool_fc_kernel<<<NG, 256, 0, stream>>>(bufA, gid, n, Wf1, bf1, Wf2, bf2, out);
}

// Round 2
// 2273.272 us; speedup vs baseline: 1.1417x; 1.1417x over previous
//
#include <hip/hip_runtime.h>
#include <hip/hip_bf16.h>

#define IN_FEATS 22
#define HID 16
#define FCH 8
#define NG 256

__device__ __forceinline__ void atomAddF(float* p, float v) {
#if defined(__HIP_PLATFORM_AMD__)
    unsafeAtomicAdd(p, v);   // HW global_atomic_add_f32
#else
    atomicAdd(p, v);
#endif
}

// ---------------- shared: input projection ----------------
// y1[node][f] = sum_k h[node][k] * W1[k][f]   (W1 stored [in,out] row-major)
__global__ __launch_bounds__(256) void proj1_kernel(
    const float* __restrict__ h, const float* __restrict__ W1,
    float* __restrict__ y1, int n) {
    int t = blockIdx.x * blockDim.x + threadIdx.x;
    int total = n * HID;
    int stride = gridDim.x * blockDim.x;
    for (int s = t; s < total; s += stride) {
        int node = s >> 4, f = s & 15;
        const float* hr = h + (long long)node * IN_FEATS;
        float acc = 0.f;
#pragma unroll
        for (int k = 0; k < IN_FEATS; ++k) acc += hr[k] * W1[k * HID + f];
        y1[s] = acc;
    }
}

// ---------------- CSR-gather path ----------------

// deg[dst[e]] += 1 (int)
__global__ __launch_bounds__(256) void degcount_kernel(
    const int* __restrict__ dst, int* __restrict__ deg, int ne) {
    int e = blockIdx.x * blockDim.x + threadIdx.x;
    if (e < ne) atomicAdd(&deg[dst[e]], 1);
}

// per-256-block exclusive scan of deg -> rowoff (block-local), blockSums[b] = total
__global__ __launch_bounds__(256) void scan_block_kernel(
    const int* __restrict__ deg, int* __restrict__ rowoff,
    int* __restrict__ blockSums, int n) {
    __shared__ int s[256];
    int i = blockIdx.x * 256 + threadIdx.x;
    int v = (i < n) ? deg[i] : 0;
    s[threadIdx.x] = v;
    __syncthreads();
    for (int off = 1; off < 256; off <<= 1) {
        int x = (threadIdx.x >= off) ? s[threadIdx.x - off] : 0;
        __syncthreads();
        s[threadIdx.x] += x;
        __syncthreads();
    }
    if (i < n) rowoff[i] = s[threadIdx.x] - v;   // exclusive within block
    if (threadIdx.x == 255) blockSums[blockIdx.x] = s[255];
}

// scan blockSums in place (exclusive). nb <= 4096. 1024 threads x 4 elems.
__global__ __launch_bounds__(1024) void scan_sums_kernel(
    int* __restrict__ blockSums, int nb) {
    __shared__ int s[1024];
    int t = threadIdx.x;
    int loc[4];
    int sum = 0;
#pragma unroll
    for (int k = 0; k < 4; ++k) {
        int idx = t * 4 + k;
        int v = (idx < nb) ? blockSums[idx] : 0;
        loc[k] = sum;          // exclusive within thread
        sum += v;
    }
    s[t] = sum;
    __syncthreads();
    for (int off = 1; off < 1024; off <<= 1) {
        int x = (t >= off) ? s[t - off] : 0;
        __syncthreads();
        s[t] += x;
        __syncthreads();
    }
    int excl = s[t] - sum;     // exclusive across threads
#pragma unroll
    for (int k = 0; k < 4; ++k) {
        int idx = t * 4 + k;
        if (idx < nb) blockSums[idx] = excl + loc[k];
    }
}

// rowoff[i] += blockSums[i/256]; cursor[i] = rowoff[i]
__global__ __launch_bounds__(256) void scan_add_kernel(
    int* __restrict__ rowoff, const int* __restrict__ blockSums,
    int* __restrict__ cursor, int n) {
    int i = blockIdx.x * 256 + threadIdx.x;
    if (i < n) {
        int r = rowoff[i] + blockSums[i >> 8];
        rowoff[i] = r;
        cursor[i] = r;
    }
}

// csr[cursor[dst[e]]++] = src[e]
__global__ __launch_bounds__(256) void fill_kernel(
    const int* __restrict__ src, const int* __restrict__ dst,
    int* __restrict__ cursor, int* __restrict__ csr, int ne) {
    int e = blockIdx.x * blockDim.x + threadIdx.x;
    if (e < ne) {
        int dn = dst[e];
        int pos = atomicAdd(&cursor[dn], 1);
        csr[pos] = src[e];
    }
}

// 16 lanes per node (lane = feat). Gather-mean over csr edge list, + bias,
// relu; if PROJ also apply 16x16 W via intra-group shuffles (layer-1 fuse).
template <bool PROJ>
__global__ __launch_bounds__(256) void agg_kernel(
    const int* __restrict__ rowoff, const int* __restrict__ deg,
    const int* __restrict__ csr, const float* __restrict__ y,
    const float* __restrict__ bias, const float* __restrict__ W,
    float* __restrict__ out, int n) {
    int sidx = blockIdx.x * blockDim.x + threadIdx.x;
    if (sidx >= n * HID) return;
    int node = sidx >> 4, f = sidx & 15;
    int lo = rowoff[node];
    int d = deg[node];
    int hi = lo + d;
    float acc = 0.f, acc2 = 0.f;
    int j = lo;
    for (; j + 1 < hi; j += 2) {
        int s0 = csr[j], s1 = csr[j + 1];
        acc += y[(s0 << 4) + f];
        acc2 += y[(s1 << 4) + f];
    }
    if (j < hi) acc += y[(csr[j] << 4) + f];
    acc += acc2;
    float val = (d > 0) ? acc / (float)d : y[sidx];
    float x = fmaxf(val + bias[f], 0.f);
    if (PROJ) {
        float o = 0.f;
#pragma unroll
        for (int k = 0; k < HID; ++k)
            o += __shfl(x, k, HID) * W[k * HID + f];
        out[sidx] = o;
    } else {
        out[sidx] = x;
    }
}

// ---------------- fallback: atomic-scatter path (proven R1) ----------------
template <bool COUNT_DEG>
__global__ __launch_bounds__(256) void scatter_kernel(
    const int* __restrict__ src, const int* __restrict__ dst,
    const float* __restrict__ y, float* __restrict__ agg,
    float* __restrict__ deg, int n_edges) {
    int t = blockIdx.x * blockDim.x + threadIdx.x;
    int total = n_edges * HID;
    int stride = gridDim.x * blockDim.x;
    for (int s = t; s < total; s += stride) {
        int e = s >> 4, f = s & 15;
        int sn = src[e], dn = dst[e];
        float v = y[(long long)sn * HID + f];
        atomAddF(&agg[(long long)dn * HID + f], v);
        if (COUNT_DEG && f == 0) atomAddF(&deg[dn], 1.0f);
    }
}

__global__ __launch_bounds__(256) void finish1_kernel(
    const float* __restrict__ agg, const float* __restrict__ deg,
    float* __restrict__ y, const float* __restrict__ b1,
    const float* __restrict__ W2, int n) {
    int i = blockIdx.x * blockDim.x + threadIdx.x;
    int stride = gridDim.x * blockDim.x;
    for (; i < n; i += stride) {
        float d = deg[i];
        float inv = d > 0.f ? 1.f / d : 0.f;
        bool mail = d > 0.f;
        const float4* ag = (const float4*)(agg + (long long)i * HID);
        const float4* yy = (const float4*)(y + (long long)i * HID);
        float x1[HID];
#pragma unroll
        for (int q = 0; q < 4; ++q) {
            float4 a = ag[q];
            float4 b = yy[q];
            float v0 = mail ? a.x * inv : b.x;
            float v1 = mail ? a.y * inv : b.y;
            float v2 = mail ? a.z * inv : b.z;
            float v3 = mail ? a.w * inv : b.w;
            x1[q * 4 + 0] = fmaxf(v0 + b1[q * 4 + 0], 0.f);
            x1[q * 4 + 1] = fmaxf(v1 + b1[q * 4 + 1], 0.f);
            x1[q * 4 + 2] = fmaxf(v2 + b1[q * 4 + 2], 0.f);
            x1[q * 4 + 3] = fmaxf(v3 + b1[q * 4 + 3], 0.f);
        }
        float out[HID];
#pragma unroll
        for (int f = 0; f < HID; ++f) out[f] = 0.f;
#pragma unroll
        for (int k = 0; k < HID; ++k) {
            float xv = x1[k];
#pragma unroll
            for (int f = 0; f < HID; ++f) out[f] += xv * W2[k * HID + f];
        }
        float4* dst4 = (float4*)(y + (long long)i * HID);
#pragma unroll
        for (int q = 0; q < 4; ++q)
            dst4[q] = make_float4(out[q * 4 + 0], out[q * 4 + 1],
                                  out[q * 4 + 2], out[q * 4 + 3]);
    }
}

__global__ __launch_bounds__(256) void finish2_kernel(
    const float* __restrict__ agg, const float* __restrict__ deg,
    float* __restrict__ y, const float* __restrict__ b2, int n) {
    int i = blockIdx.x * blockDim.x + threadIdx.x;
    int stride = gridDim.x * blockDim.x;
    for (; i < n; i += stride) {
        float d = deg[i];
        float inv = d > 0.f ? 1.f / d : 0.f;
        bool mail = d > 0.f;
        const float4* ag = (const float4*)(agg + (long long)i * HID);
        float4* yy = (float4*)(y + (long long)i * HID);
#pragma unroll
        for (int q = 0; q < 4; ++q) {
            float4 a = ag[q];
            float4 b = yy[q];
            float v0 = mail ? a.x * inv : b.x;
            float v1 = mail ? a.y * inv : b.y;
            float v2 = mail ? a.z * inv : b.z;
            float v3 = mail ? a.w * inv : b.w;
            yy[q] = make_float4(fmaxf(v0 + b2[q * 4 + 0], 0.f),
                                fmaxf(v1 + b2[q * 4 + 1], 0.f),
                                fmaxf(v2 + b2[q * 4 + 2], 0.f),
                                fmaxf(v3 + b2[q * 4 + 3], 0.f));
        }
    }
}

// ---------------- pooling + FC head ----------------
__global__ __launch_bounds__(256) void pool_fc_kernel(
    const float* __restrict__ x2, const int* __restrict__ gid, int n,
    const float* __restrict__ Wf1, const float* __restrict__ bf1,
    const float* __restrict__ Wf2, const float* __restrict__ bf2,
    float* __restrict__ out) {
    int g = blockIdx.x;
    int lo, hi;
    {
        int a = 0, b = n;
        while (a < b) { int m = (a + b) >> 1; if (gid[m] < g) a = m + 1; else b = m; }
        lo = a;
        b = n;
        while (a < b) { int m = (a + b) >> 1; if (gid[m] < g + 1) a = m + 1; else b = m; }
        hi = a;
    }
    int cnt = hi - lo;
    float acc[HID];
#pragma unroll
    for (int k = 0; k < HID; ++k) acc[k] = 0.f;
    for (int i = lo + threadIdx.x; i < hi; i += blockDim.x) {
        const float4* p = (const float4*)(x2 + (long long)i * HID);
#pragma unroll
        for (int q = 0; q < 4; ++q) {
            float4 v = p[q];
            acc[q * 4 + 0] += v.x; acc[q * 4 + 1] += v.y;
            acc[q * 4 + 2] += v.z; acc[q * 4 + 3] += v.w;
        }
    }
    __shared__ float smem[256][HID];
#pragma unroll
    for (int k = 0; k < HID; ++k) smem[threadIdx.x][k] = acc[k];
    __syncthreads();
    for (int off = 128; off > 0; off >>= 1) {
        if (threadIdx.x < off)
            for (int k = 0; k < HID; ++k)
                smem[threadIdx.x][k] += smem[threadIdx.x + off][k];
        __syncthreads();
    }
    if (threadIdx.x == 0) {
        float inv = cnt > 0 ? 1.f / (float)cnt : 0.f;
        float hg[HID];
        for (int k = 0; k < HID; ++k) hg[k] = smem[0][k] * inv;
        float f1[FCH];
        for (int j = 0; j < FCH; ++j) {
            float a = bf1[j];
            for (int k = 0; k < HID; ++k) a += hg[k] * Wf1[k * FCH + j];
            f1[j] = a;
        }
        float o = bf2[0];
        for (int j = 0; j < FCH; ++j) o += f1[j] * Wf2[j];
        out[g] = 1.f / (1.f + expf(-o));
    }
}

extern "C" void kernel_launch(void* const* d_in, const int* in_sizes, int n_in,
                              void* d_out, int out_size, void* d_ws, size_t ws_size,
                              hipStream_t stream) {
    const float* h   = (const float*)d_in[0];
    const int*   src = (const int*)d_in[1];
    const int*   dst = (const int*)d_in[2];
    const int*   gid = (const int*)d_in[3];
    const float* W1  = (const float*)d_in[4];
    const float* b1  = (const float*)d_in[5];
    const float* W2  = (const float*)d_in[6];
    const float* b2  = (const float*)d_in[7];
    const float* Wf1 = (const float*)d_in[8];
    const float* bf1 = (const float*)d_in[9];
    const float* Wf2 = (const float*)d_in[10];
    const float* bf2 = (const float*)d_in[11];
    float* out = (float*)d_out;

    int n  = in_sizes[3];     // N_NODES
    int ne = in_sizes[1];     // N_EDGES

    size_t featB = (size_t)n * HID * 4;   // 64 MB
    size_t intB  = (size_t)n * 4;         // 4 MB
    int nb = (n + 255) / 256;             // scan blocks (<= 4096 for n <= 1M)

    size_t need = 3 * featB + 3 * intB + (size_t)4096 * 4;

    char* ws = (char*)d_ws;
    if (ws_size >= need && nb <= 4096) {
        // ---------- CSR gather path ----------
        float* bufA   = (float*)ws;                       // y1 / x2
        float* bufB   = (float*)(ws + featB);             // y2
        int*   csr    = (int*)  (ws + 2 * featB);         // ne entries (<= featB)
        int*   deg    = (int*)  (ws + 3 * featB);
        int*   rowoff = (int*)  (ws + 3 * featB + intB);
        int*   cursor = (int*)  (ws + 3 * featB + 2 * intB);
        int*   bsums  = (int*)  (ws + 3 * featB + 3 * intB);

        hipMemsetAsync(deg, 0, intB, stream);

        int gE = (ne + 255) / 256;            // edge-parallel grids
        int gF = (n * HID + 255) / 256;       // feat-parallel grids

        proj1_kernel<<<4096, 256, 0, stream>>>(h, W1, bufA, n);
        degcount_kernel<<<gE, 256, 0, stream>>>(dst, deg, ne);
        scan_block_kernel<<<nb, 256, 0, stream>>>(deg, rowoff, bsums, n);
        scan_sums_kernel<<<1, 1024, 0, stream>>>(bsums, nb);
        scan_add_kernel<<<nb, 256, 0, stream>>>(rowoff, bsums, cursor, n);
        fill_kernel<<<gE, 256, 0, stream>>>(src, dst, cursor, csr, ne);
        agg_kernel<true><<<gF, 256, 0, stream>>>(rowoff, deg, csr, bufA, b1, W2, bufB, n);
        agg_kernel<false><<<gF, 256, 0, stream>>>(rowoff, deg, csr, bufB, b2, nullptr, bufA, n);
        pool_fc_kernel<<<NG, 256, 0, stream>>>(bufA, gid, n, Wf1, bf1, Wf2, bf2, out);
    } else {
        // ---------- fallback: atomic scatter path ----------
        float* bufA = (float*)ws;
        float* bufB = (float*)(ws + featB);
        float* deg  = (float*)(ws + 2 * featB);

        hipMemsetAsync(bufB, 0, featB, stream);
        hipMemsetAsync(deg, 0, intB, stream);

        proj1_kernel<<<4096, 256, 0, stream>>>(h, W1, bufA, n);
        scatter_kernel<true><<<8192, 256, 0, stream>>>(src, dst, bufA, bufB, deg, ne);
        finish1_kernel<<<4096, 256, 0, stream>>>(bufB, deg, bufA, b1, W2, n);
        hipMemsetAsync(bufB, 0, featB, stream);
        scatter_kernel<false><<<8192, 256, 0, stream>>>(src, dst, bufA, bufB, deg, ne);
        finish2_kernel<<<4096, 256, 0, stream>>>(bufB, deg, bufA, b2, n);
        pool_fc_kernel<<<NG, 256, 0, stream>>>(bufA, gid, n, Wf1, bf1, Wf2, bf2, out);
    }
}